// Round 2
// baseline (472.871 us; speedup 1.0000x reference)
//
#include <hip/hip_runtime.h>

typedef __bf16 bf16x8 __attribute__((ext_vector_type(8)));
typedef __bf16 bf16x4 __attribute__((ext_vector_type(4)));
typedef float floatx4 __attribute__((ext_vector_type(4)));

__device__ __forceinline__ __bf16 f2bf(float f) {
  union { float f; unsigned u; } x; x.f = f;
  unsigned r = (x.u + 0x7FFFu + ((x.u >> 16) & 1u)) >> 16;
  union { unsigned short u; __bf16 b; } o; o.u = (unsigned short)r; return o.b;
}
__device__ __forceinline__ float bf2f(__bf16 b) {
  union { unsigned short u; __bf16 b; } i; i.b = b;
  union { unsigned u; float f; } y; y.u = ((unsigned)i.u) << 16; return y.f;
}

#define MFMA16(a, b, c) __builtin_amdgcn_mfma_f32_16x16x32_bf16(a, b, c, 0, 0, 0)

// ---------------- prep: transpose + bf16-convert weights ----------------
__global__ __launch_bounds__(256) void prep_weights(
    const float* __restrict__ W1, const float* __restrict__ WQ,
    const float* __restrict__ WK, const float* __restrict__ WV,
    const float* __restrict__ W2,
    __bf16* __restrict__ w1t, __bf16* __restrict__ wqt,
    __bf16* __restrict__ wkt, __bf16* __restrict__ wvt,
    __bf16* __restrict__ w2t) {
  int i = blockIdx.x * 256 + threadIdx.x;
  if (i < 147456) { int n = i / 768, k = i % 768; w1t[i] = f2bf(W1[k * 192 + n]); return; }
  i -= 147456;
  if (i < 36864) { int n = i / 192, k = i % 192; wqt[i] = f2bf(WQ[k * 192 + n]); return; }
  i -= 36864;
  if (i < 36864) { int n = i / 192, k = i % 192; wkt[i] = f2bf(WK[k * 192 + n]); return; }
  i -= 36864;
  if (i < 36864) { int n = i / 192, k = i % 192; wvt[i] = f2bf(WV[k * 192 + n]); return; }
  i -= 36864;
  if (i < 147456) { int n = i / 192, k = i % 192; w2t[i] = f2bf(W2[k * 768 + n]); return; }
}

// xpos tables: [32][192] each (repeat-2 applied)
__global__ __launch_bounds__(256) void prep_tables(
    float* __restrict__ cq, float* __restrict__ sq,
    float* __restrict__ ck, float* __restrict__ sk) {
  int i = blockIdx.x * 256 + threadIdx.x;
  if (i >= 32 * 96) return;
  int s = i / 96, f = i % 96;
  float base = (2.f * f + 0.4f * 192.f) / (1.4f * 192.f);
  float scale = powf(base, (float)s / 512.f);
  float invf = powf(10000.f, -(float)f / 96.f);
  float ang = (float)s * invf;
  float sn = sinf(ang), cs = cosf(ang);
  int o = s * 192 + 2 * f;
  cq[o] = cs * scale; cq[o + 1] = cs * scale;
  sq[o] = sn * scale; sq[o + 1] = sn * scale;
  ck[o] = cs / scale; ck[o + 1] = cs / scale;
  sk[o] = sn / scale; sk[o + 1] = sn / scale;
}

// ---------------- main fused kernel: one WG per 32-token sequence ----------------
__global__ __launch_bounds__(256, 2) void retnet_main(
    const float* __restrict__ x, const float* __restrict__ b1,
    const float* __restrict__ b2, const float* __restrict__ ln_g,
    const float* __restrict__ ln_b,
    const __bf16* __restrict__ w1t, const __bf16* __restrict__ wqt,
    const __bf16* __restrict__ wkt, const __bf16* __restrict__ wvt,
    const __bf16* __restrict__ w2t,
    const float* __restrict__ cq, const float* __restrict__ sq,
    const float* __restrict__ ck, const float* __restrict__ sk,
    float* __restrict__ out) {
  // LDS: region A [0,49152): xr bf16 32x768; later Q(0) K(6144) Vt(12288) ret(18432)
  //      region B [49152,61440): xdown/h bf16 32x192
  //      region C [61440,63488): att bf16 32x32
  __shared__ __align__(16) char smem[63488];
  __bf16* A = (__bf16*)smem;
  __bf16* Q = A;
  __bf16* Kl = A + 6144;
  __bf16* Vt = A + 12288;   // [d][s] layout, stride 32
  __bf16* ret = A + 18432;  // [s][d] stride 192
  __bf16* h = (__bf16*)(smem + 49152);
  __bf16* att = (__bf16*)(smem + 61440);

  const int tid = threadIdx.x;
  const int wv = tid >> 6;
  const int lane = tid & 63;
  const int l16 = lane & 15;
  const int quad = lane >> 4;
  const int kof = quad * 8;
  const int p = blockIdx.x;
  const float* xblk = x + (size_t)p * 32 * 768;

  // Phase 0: load 32x768 fp32 -> bf16 LDS
#pragma unroll 6
  for (int i = 0; i < 24; ++i) {
    int q4 = i * 256 + tid;
    float4 v = ((const float4*)xblk)[q4];
    bf16x4 b; b[0] = f2bf(v.x); b[1] = f2bf(v.y); b[2] = f2bf(v.z); b[3] = f2bf(v.w);
    *(bf16x4*)(A + q4 * 4) = b;
  }
  __syncthreads();

  // Phase 1: x_down = xr @ W1 + b1  (M=32,N=192,K=768) -> h (bf16)
  {
    floatx4 acc[2][3] = {};
#pragma unroll 4
    for (int kk = 0; kk < 768; kk += 32) {
      bf16x8 a0 = *(const bf16x8*)(A + l16 * 768 + kk + kof);
      bf16x8 a1 = *(const bf16x8*)(A + (16 + l16) * 768 + kk + kof);
#pragma unroll
      for (int t = 0; t < 3; ++t) {
        bf16x8 bb = *(const bf16x8*)(w1t + (size_t)(wv * 48 + t * 16 + l16) * 768 + kk + kof);
        acc[0][t] = MFMA16(a0, bb, acc[0][t]);
        acc[1][t] = MFMA16(a1, bb, acc[1][t]);
      }
    }
#pragma unroll
    for (int m = 0; m < 2; ++m)
#pragma unroll
      for (int t = 0; t < 3; ++t) {
        int col = wv * 48 + t * 16 + l16;
        float bias = b1[col];
#pragma unroll
        for (int r = 0; r < 4; ++r) {
          int row = m * 16 + quad * 4 + r;
          h[row * 192 + col] = f2bf(acc[m][t][r] + bias);
        }
      }
  }
  __syncthreads();

  // Phase 2: LayerNorm rows of h (in place). 8 threads per row.
  {
    int r = tid >> 3, g = tid & 7;
    float vals[24]; float s = 0.f, s2 = 0.f;
#pragma unroll
    for (int j = 0; j < 24; ++j) {
      float v = bf2f(h[r * 192 + g * 24 + j]);
      vals[j] = v; s += v; s2 += v * v;
    }
#pragma unroll
    for (int o = 1; o < 8; o <<= 1) { s += __shfl_xor(s, o); s2 += __shfl_xor(s2, o); }
    float mu = s * (1.f / 192.f);
    float var = s2 * (1.f / 192.f) - mu * mu;
    float rstd = rsqrtf(var + 1e-5f);
#pragma unroll
    for (int j = 0; j < 24; ++j) {
      int c = g * 24 + j;
      h[r * 192 + c] = f2bf((vals[j] - mu) * rstd * ln_g[c] + ln_b[c]);
    }
  }
  __syncthreads();

  // Phase 3: Q/K/V = h @ W (M=32,N=192,K=192); xpos on Q,K; V stored transposed
  auto gemm_h = [&](const __bf16* __restrict__ W, floatx4 (&acc)[2][3]) {
#pragma unroll
    for (int kk = 0; kk < 192; kk += 32) {
      bf16x8 a0 = *(const bf16x8*)(h + l16 * 192 + kk + kof);
      bf16x8 a1 = *(const bf16x8*)(h + (16 + l16) * 192 + kk + kof);
#pragma unroll
      for (int t = 0; t < 3; ++t) {
        bf16x8 bb = *(const bf16x8*)(W + (size_t)(wv * 48 + t * 16 + l16) * 192 + kk + kof);
        acc[0][t] = MFMA16(a0, bb, acc[0][t]);
        acc[1][t] = MFMA16(a1, bb, acc[1][t]);
      }
    }
  };
  {
    floatx4 acc[2][3] = {};
    gemm_h(wqt, acc);
#pragma unroll
    for (int m = 0; m < 2; ++m)
#pragma unroll
      for (int t = 0; t < 3; ++t) {
        int col = wv * 48 + t * 16 + l16;
#pragma unroll
        for (int r = 0; r < 4; ++r) {
          int row = m * 16 + quad * 4 + r;
          float v = acc[m][t][r];
          float pr = __shfl_xor(v, 1);
          float o = v * cq[row * 192 + col] + ((lane & 1) ? pr : -pr) * sq[row * 192 + col];
          Q[row * 192 + col] = f2bf(o);
        }
      }
  }
  {
    floatx4 acc[2][3] = {};
    gemm_h(wkt, acc);
#pragma unroll
    for (int m = 0; m < 2; ++m)
#pragma unroll
      for (int t = 0; t < 3; ++t) {
        int col = wv * 48 + t * 16 + l16;
#pragma unroll
        for (int r = 0; r < 4; ++r) {
          int row = m * 16 + quad * 4 + r;
          float v = acc[m][t][r];
          float pr = __shfl_xor(v, 1);
          float o = v * ck[row * 192 + col] + ((lane & 1) ? pr : -pr) * sk[row * 192 + col];
          Kl[row * 192 + col] = f2bf(o);
        }
      }
  }
  {
    floatx4 acc[2][3] = {};
    gemm_h(wvt, acc);
#pragma unroll
    for (int m = 0; m < 2; ++m)
#pragma unroll
      for (int t = 0; t < 3; ++t) {
        int col = wv * 48 + t * 16 + l16;
        int s0 = m * 16 + quad * 4;
        bf16x4 pk;
#pragma unroll
        for (int r = 0; r < 4; ++r) pk[r] = f2bf(acc[m][t][r]);
        *(bf16x4*)(Vt + col * 32 + s0) = pk;  // [d][s]
      }
  }
  __syncthreads();

  // Phase 4: att = (Q @ K^T) * decay  (32x32); one 16x16 tile per wave
  {
    int mt = wv >> 1, nt = wv & 1;
    floatx4 acc = {0.f, 0.f, 0.f, 0.f};
#pragma unroll
    for (int kk = 0; kk < 192; kk += 32) {
      bf16x8 a = *(const bf16x8*)(Q + (mt * 16 + l16) * 192 + kk + kof);
      bf16x8 bb = *(const bf16x8*)(Kl + (nt * 16 + l16) * 192 + kk + kof);
      acc = MFMA16(a, bb, acc);
    }
#pragma unroll
    for (int r = 0; r < 4; ++r) {
      int i = mt * 16 + quad * 4 + r;
      int j = nt * 16 + l16;
      float v = (i >= j) ? acc[r] * exp2f((float)(j - i)) : 0.f;
      att[i * 32 + j] = f2bf(v);
    }
  }
  __syncthreads();

  // Phase 5: ret = att @ V  (M=32,N=192,K=32)
  {
    floatx4 acc[2][3] = {};
    bf16x8 a0 = *(const bf16x8*)(att + l16 * 32 + kof);
    bf16x8 a1 = *(const bf16x8*)(att + (16 + l16) * 32 + kof);
#pragma unroll
    for (int t = 0; t < 3; ++t) {
      bf16x8 bb = *(const bf16x8*)(Vt + (wv * 48 + t * 16 + l16) * 32 + kof);
      acc[0][t] = MFMA16(a0, bb, acc[0][t]);
      acc[1][t] = MFMA16(a1, bb, acc[1][t]);
    }
#pragma unroll
    for (int m = 0; m < 2; ++m)
#pragma unroll
      for (int t = 0; t < 3; ++t) {
        int col = wv * 48 + t * 16 + l16;
#pragma unroll
        for (int r = 0; r < 4; ++r) {
          int row = m * 16 + quad * 4 + r;
          ret[row * 192 + col] = f2bf(acc[m][t][r]);
        }
      }
  }
  __syncthreads();

  // Phase 6: out = x + ret @ W2 + b2  (M=32,N=768,K=192); wave owns 192 cols
  {
    bf16x8 af[2][6];
#pragma unroll
    for (int k6 = 0; k6 < 6; ++k6) {
      af[0][k6] = *(const bf16x8*)(ret + l16 * 192 + k6 * 32 + kof);
      af[1][k6] = *(const bf16x8*)(ret + (16 + l16) * 192 + k6 * 32 + kof);
    }
#pragma unroll
    for (int g = 0; g < 4; ++g) {
      floatx4 acc[2][3] = {};
#pragma unroll
      for (int k6 = 0; k6 < 6; ++k6) {
#pragma unroll
        for (int t = 0; t < 3; ++t) {
          bf16x8 bb = *(const bf16x8*)(w2t + (size_t)(wv * 192 + g * 48 + t * 16 + l16) * 192 + k6 * 32 + kof);
          acc[0][t] = MFMA16(af[0][k6], bb, acc[0][t]);
          acc[1][t] = MFMA16(af[1][k6], bb, acc[1][t]);
        }
      }
#pragma unroll
      for (int m = 0; m < 2; ++m)
#pragma unroll
        for (int t = 0; t < 3; ++t) {
          int col = wv * 192 + g * 48 + t * 16 + l16;
          float bias = b2[col];
#pragma unroll
          for (int r = 0; r < 4; ++r) {
            int row = m * 16 + quad * 4 + r;
            size_t gi = (size_t)p * 24576 + row * 768 + col;
            out[gi] = xblk[row * 768 + col] + acc[m][t][r] + bias;
          }
        }
    }
  }
}

extern "C" void kernel_launch(void* const* d_in, const int* in_sizes, int n_in,
                              void* d_out, int out_size, void* d_ws, size_t ws_size,
                              hipStream_t stream) {
  const float* x = (const float*)d_in[0];
  const float* W1 = (const float*)d_in[1];
  const float* b1 = (const float*)d_in[2];
  const float* W2 = (const float*)d_in[3];
  const float* b2 = (const float*)d_in[4];
  const float* lng = (const float*)d_in[5];
  const float* lnb = (const float*)d_in[6];
  const float* WQ = (const float*)d_in[7];
  const float* WK = (const float*)d_in[8];
  const float* WV = (const float*)d_in[9];
  float* out = (float*)d_out;

  char* ws = (char*)d_ws;
  __bf16* w1t = (__bf16*)(ws + 0);
  __bf16* wqt = (__bf16*)(ws + 294912);
  __bf16* wkt = (__bf16*)(ws + 368640);
  __bf16* wvt = (__bf16*)(ws + 442368);
  __bf16* w2t = (__bf16*)(ws + 516096);
  float* cq = (float*)(ws + 811008);
  float* sq = cq + 6144;
  float* ck = sq + 6144;
  float* sk = ck + 6144;

  hipLaunchKernelGGL(prep_weights, dim3(1584), dim3(256), 0, stream,
                     W1, WQ, WK, WV, W2, w1t, wqt, wkt, wvt, w2t);
  hipLaunchKernelGGL(prep_tables, dim3(12), dim3(256), 0, stream, cq, sq, ck, sk);
  hipLaunchKernelGGL(retnet_main, dim3(1568), dim3(256), 0, stream,
                     x, b1, b2, lng, lnb, w1t, wqt, wkt, wvt, w2t, cq, sq, ck, sk, out);
}